// Round 1
// baseline (219.181 us; speedup 1.0000x reference)
//
#include <hip/hip_runtime.h>
#include <hip/hip_bf16.h>

// Sparse Conv3d(32,32,k=2,s=2) kernel-map form:
//   out[out_idx[p], d] += sum_c x[p,c] * W[k_idx[p], c, d]
// Strategy: 16-point MFMA tiles (16x16x32 bf16, K=32 = full C in one MFMA).
// Kernel-offset selection folded into the MFMA chain: for each k, zero the
// A-fragment rows whose k_idx != k, accumulate into the same acc. Scatter via
// atomicAdd (<=8 contenders/voxel). W pre-repacked to B-fragment lane order.

typedef __attribute__((ext_vector_type(8))) short bf16x8;   // 8 bf16 = 4 VGPRs
typedef __attribute__((ext_vector_type(4))) float f32x4;    // 4 fp32 acc

union ABFrag { bf16x8 v; int i[4]; };

__device__ __forceinline__ unsigned short f2bf(float f) {
    union { float f; unsigned u; } v; v.f = f;
    unsigned r = v.u + 0x7FFFu + ((v.u >> 16) & 1u);   // RNE
    return (unsigned short)(r >> 16);
}

// Repack W[k][c][d] (fp32) -> WB in exact B-fragment lane order:
// WB[((k*2+half)*64 + lane)*8 + j] = bf16(W[k][(lane>>4)*8 + j][half*16 + (lane&15)])
// so each lane's B fragment is one contiguous 16B load. Total 16 KB.
__global__ void prep_w_kernel(const float* __restrict__ W,
                              unsigned short* __restrict__ WB) {
    int t = blockIdx.x * blockDim.x + threadIdx.x;   // 0..8191
    if (t >= 8 * 2 * 64 * 8) return;
    int j    = t & 7;
    int lane = (t >> 3) & 63;
    int half = (t >> 9) & 1;
    int k    = t >> 10;
    int c = (lane >> 4) * 8 + j;
    int d = half * 16 + (lane & 15);
    WB[t] = f2bf(W[k * 1024 + c * 32 + d]);
}

__global__ __launch_bounds__(256) void conv_kernel(
    const float* __restrict__ x,
    const unsigned short* __restrict__ WB,
    const int* __restrict__ k_idx,
    const int* __restrict__ out_idx,
    float* __restrict__ out,
    int n)
{
    const int lane = threadIdx.x & 63;
    const int wv   = threadIdx.x >> 6;
    const int base = (blockIdx.x * 4 + wv) * 16;      // 16 points per wave tile
    if (base >= n) return;

    const int row  = lane & 15;     // A-fragment: m = lane&15
    const int quad = lane >> 4;     // A-fragment: k-cols = quad*8 + j
    const int p = base + row;

    int krow = -1;
    ABFrag a; a.i[0] = 0; a.i[1] = 0; a.i[2] = 0; a.i[3] = 0;
    if (p < n) {
        krow = k_idx[p];
        const float* xp = x + (size_t)p * 32 + quad * 8;
        float4 x0 = *(const float4*)xp;
        float4 x1 = *(const float4*)(xp + 4);
        unsigned short h0 = f2bf(x0.x), h1 = f2bf(x0.y), h2 = f2bf(x0.z), h3 = f2bf(x0.w);
        unsigned short h4 = f2bf(x1.x), h5 = f2bf(x1.y), h6 = f2bf(x1.z), h7 = f2bf(x1.w);
        a.i[0] = (int)h0 | ((int)h1 << 16);
        a.i[1] = (int)h2 | ((int)h3 << 16);
        a.i[2] = (int)h4 | ((int)h5 << 16);
        a.i[3] = (int)h6 | ((int)h7 << 16);
    }

    f32x4 acc0 = {0.f, 0.f, 0.f, 0.f};   // channels 0..15
    f32x4 acc1 = {0.f, 0.f, 0.f, 0.f};   // channels 16..31

#pragma unroll
    for (int k = 0; k < 8; ++k) {
        // B fragments: one 16B load each; WB (16 KB) is L1-resident.
        bf16x8 b0 = *(const bf16x8*)(WB + ((size_t)(k * 2 + 0) * 64 + lane) * 8);
        bf16x8 b1 = *(const bf16x8*)(WB + ((size_t)(k * 2 + 1) * 64 + lane) * 8);
        // Mask A rows whose kernel offset != k (4 cndmask), so summing over k
        // performs the per-point selection implicitly.
        const bool keep = (krow == k);
        ABFrag ak;
        ak.i[0] = keep ? a.i[0] : 0;
        ak.i[1] = keep ? a.i[1] : 0;
        ak.i[2] = keep ? a.i[2] : 0;
        ak.i[3] = keep ? a.i[3] : 0;
        acc0 = __builtin_amdgcn_mfma_f32_16x16x32_bf16(ak.v, b0, acc0, 0, 0, 0);
        acc1 = __builtin_amdgcn_mfma_f32_16x16x32_bf16(ak.v, b1, acc1, 0, 0, 0);
    }

    // C/D layout (m89-verified): col = lane&15 (= output channel within half),
    // row = quad*4 + r (= point within tile). Scatter-add.
#pragma unroll
    for (int r = 0; r < 4; ++r) {
        int m = quad * 4 + r;
        int p2 = base + m;
        if (p2 < n) {
            int oi = out_idx[p2];
            float* op = out + (size_t)oi * 32 + (lane & 15);
            atomicAdd(op,      acc0[r]);
            atomicAdd(op + 16, acc1[r]);
        }
    }
}

extern "C" void kernel_launch(void* const* d_in, const int* in_sizes, int n_in,
                              void* d_out, int out_size, void* d_ws, size_t ws_size,
                              hipStream_t stream) {
    const float* x       = (const float*)d_in[0];
    const float* W       = (const float*)d_in[1];
    const int*   k_idx   = (const int*)d_in[2];
    const int*   out_idx = (const int*)d_in[3];
    const int n = in_sizes[2];

    unsigned short* WB = (unsigned short*)d_ws;      // 16 KB repacked W
    float* out = (float*)d_out;

    // d_out is poisoned 0xAA before every timed call -> zero it (async, capturable).
    hipMemsetAsync(d_out, 0, (size_t)out_size * sizeof(float), stream);

    prep_w_kernel<<<32, 256, 0, stream>>>(W, WB);

    int blocks = (n + 63) / 64;                       // 64 points per block (4 waves)
    if (blocks > 0)
        conv_kernel<<<blocks, 256, 0, stream>>>(x, WB, k_idx, out_idx, out, n);
}

// Round 2
// 181.652 us; speedup vs baseline: 1.2066x; 1.2066x over previous
//
#include <hip/hip_runtime.h>
#include <hip/hip_bf16.h>

// Sparse Conv3d(32,32,k=2,s=2) kernel-map form:
//   out[out_idx[p], d] += sum_c x[p,c] * W[k_idx[p], c, d]
//
// R2 strategy: k=2,s=2 means each input point owns a UNIQUE (out_voxel, k)
// slot. Build inverse map child[o][k]=p with plain stores (no atomics), then
// one wave per 16 output voxels: for each k, gather the child's x-row, MFMA
// (16x16x32 bf16) against pre-repacked W[k], accumulate, plain-store the
// finished row. Zero atomics, no d_out memset (every voxel has >=1 child).

typedef __attribute__((ext_vector_type(8))) short bf16x8;   // 8 bf16 = 4 VGPRs
typedef __attribute__((ext_vector_type(4))) float f32x4;    // 4 fp32 acc

union ABFrag { bf16x8 v; int i[4]; };

__device__ __forceinline__ unsigned short f2bf(float f) {
    union { float f; unsigned u; } v; v.f = f;
    unsigned r = v.u + 0x7FFFu + ((v.u >> 16) & 1u);   // RNE
    return (unsigned short)(r >> 16);
}

// Repack W[k][c][d] (fp32) -> WB in exact B-fragment lane order (16 KB):
// WB[((k*2+half)*64 + lane)*8 + j] = bf16(W[k][(lane>>4)*8 + j][half*16 + (lane&15)])
__global__ void prep_w_kernel(const float* __restrict__ W,
                              unsigned short* __restrict__ WB) {
    int t = blockIdx.x * blockDim.x + threadIdx.x;   // 0..8191
    if (t >= 8 * 2 * 64 * 8) return;
    int j    = t & 7;
    int lane = (t >> 3) & 63;
    int half = (t >> 9) & 1;
    int k    = t >> 10;
    int c = (lane >> 4) * 8 + j;
    int d = half * 16 + (lane & 15);
    WB[t] = f2bf(W[k * 1024 + c * 32 + d]);
}

// Inverse map: each point owns a unique (out,k) slot -> plain store.
__global__ __launch_bounds__(256) void build_map_kernel(
    const int* __restrict__ k_idx, const int* __restrict__ out_idx,
    int* __restrict__ child, int n) {
    int t = blockIdx.x * blockDim.x + threadIdx.x;
    if (t < n) child[(size_t)out_idx[t] * 8 + k_idx[t]] = t;
}

__global__ __launch_bounds__(256) void conv_gather_kernel(
    const float* __restrict__ x,
    const unsigned short* __restrict__ WB,
    const int* __restrict__ child,
    float* __restrict__ out,
    int num_out)
{
    const int lane  = threadIdx.x & 63;
    const int wv    = threadIdx.x >> 6;
    const int obase = (blockIdx.x * 4 + wv) * 16;     // 16 out voxels per wave
    if (obase >= num_out) return;

    const int row  = lane & 15;     // A-frag: m = lane&15 (out voxel within tile)
    const int quad = lane >> 4;     // A-frag: k-cols = quad*8 + j
    const int o = obase + row;

    // All 8 child indices for this row: one 32B region, redundantly loaded
    // by the 4 quads (L1-hot).
    int4 c0 = make_int4(-1, -1, -1, -1), c1 = make_int4(-1, -1, -1, -1);
    if (o < num_out) {
        const int4* cp = (const int4*)(child + (size_t)o * 8);
        c0 = cp[0]; c1 = cp[1];
    }
    int pk[8] = {c0.x, c0.y, c0.z, c0.w, c1.x, c1.y, c1.z, c1.w};

    // Issue all gathers up front (8 x 32B per lane in flight).
    float4 xa[8], xb[8];
#pragma unroll
    for (int k = 0; k < 8; ++k) {
        xa[k] = make_float4(0.f, 0.f, 0.f, 0.f);
        xb[k] = make_float4(0.f, 0.f, 0.f, 0.f);
        if (pk[k] >= 0) {
            const float* xp = x + (size_t)pk[k] * 32 + quad * 8;
            xa[k] = *(const float4*)xp;
            xb[k] = *(const float4*)(xp + 4);
        }
    }

    f32x4 acc0 = {0.f, 0.f, 0.f, 0.f};   // channels 0..15
    f32x4 acc1 = {0.f, 0.f, 0.f, 0.f};   // channels 16..31

#pragma unroll
    for (int k = 0; k < 8; ++k) {
        ABFrag a;
        a.i[0] = (int)f2bf(xa[k].x) | ((int)f2bf(xa[k].y) << 16);
        a.i[1] = (int)f2bf(xa[k].z) | ((int)f2bf(xa[k].w) << 16);
        a.i[2] = (int)f2bf(xb[k].x) | ((int)f2bf(xb[k].y) << 16);
        a.i[3] = (int)f2bf(xb[k].z) | ((int)f2bf(xb[k].w) << 16);
        bf16x8 b0 = *(const bf16x8*)(WB + ((size_t)(k * 2 + 0) * 64 + lane) * 8);
        bf16x8 b1 = *(const bf16x8*)(WB + ((size_t)(k * 2 + 1) * 64 + lane) * 8);
        acc0 = __builtin_amdgcn_mfma_f32_16x16x32_bf16(a.v, b0, acc0, 0, 0, 0);
        acc1 = __builtin_amdgcn_mfma_f32_16x16x32_bf16(a.v, b1, acc1, 0, 0, 0);
    }

    // C/D layout: col = lane&15 (channel), row = quad*4 + r (voxel). Plain store.
#pragma unroll
    for (int r = 0; r < 4; ++r) {
        int oo = obase + quad * 4 + r;
        if (oo < num_out) {
            float* op = out + (size_t)oo * 32 + (lane & 15);
            op[0]  = acc0[r];
            op[16] = acc1[r];
        }
    }
}

// ---- R1 fallback (atomic scatter) in case ws_size can't hold the map ----
__global__ __launch_bounds__(256) void conv_atomic_kernel(
    const float* __restrict__ x, const unsigned short* __restrict__ WB,
    const int* __restrict__ k_idx, const int* __restrict__ out_idx,
    float* __restrict__ out, int n)
{
    const int lane = threadIdx.x & 63;
    const int wv   = threadIdx.x >> 6;
    const int base = (blockIdx.x * 4 + wv) * 16;
    if (base >= n) return;
    const int row = lane & 15, quad = lane >> 4;
    const int p = base + row;
    int krow = -1;
    ABFrag a; a.i[0] = a.i[1] = a.i[2] = a.i[3] = 0;
    if (p < n) {
        krow = k_idx[p];
        const float* xp = x + (size_t)p * 32 + quad * 8;
        float4 x0 = *(const float4*)xp;
        float4 x1 = *(const float4*)(xp + 4);
        a.i[0] = (int)f2bf(x0.x) | ((int)f2bf(x0.y) << 16);
        a.i[1] = (int)f2bf(x0.z) | ((int)f2bf(x0.w) << 16);
        a.i[2] = (int)f2bf(x1.x) | ((int)f2bf(x1.y) << 16);
        a.i[3] = (int)f2bf(x1.z) | ((int)f2bf(x1.w) << 16);
    }
    f32x4 acc0 = {0.f,0.f,0.f,0.f}, acc1 = {0.f,0.f,0.f,0.f};
#pragma unroll
    for (int k = 0; k < 8; ++k) {
        bf16x8 b0 = *(const bf16x8*)(WB + ((size_t)(k*2+0)*64 + lane)*8);
        bf16x8 b1 = *(const bf16x8*)(WB + ((size_t)(k*2+1)*64 + lane)*8);
        const bool keep = (krow == k);
        ABFrag ak;
        ak.i[0] = keep ? a.i[0] : 0; ak.i[1] = keep ? a.i[1] : 0;
        ak.i[2] = keep ? a.i[2] : 0; ak.i[3] = keep ? a.i[3] : 0;
        acc0 = __builtin_amdgcn_mfma_f32_16x16x32_bf16(ak.v, b0, acc0, 0, 0, 0);
        acc1 = __builtin_amdgcn_mfma_f32_16x16x32_bf16(ak.v, b1, acc1, 0, 0, 0);
    }
#pragma unroll
    for (int r = 0; r < 4; ++r) {
        int p2 = base + quad * 4 + r;
        if (p2 < n) {
            int oi = out_idx[p2];
            float* op = out + (size_t)oi * 32 + (lane & 15);
            atomicAdd(op,      acc0[r]);
            atomicAdd(op + 16, acc1[r]);
        }
    }
}

extern "C" void kernel_launch(void* const* d_in, const int* in_sizes, int n_in,
                              void* d_out, int out_size, void* d_ws, size_t ws_size,
                              hipStream_t stream) {
    const float* x       = (const float*)d_in[0];
    const float* W       = (const float*)d_in[1];
    const int*   k_idx   = (const int*)d_in[2];
    const int*   out_idx = (const int*)d_in[3];
    const int n = in_sizes[2];
    const int num_out = out_size / 32;           // C=32 channels per voxel
    float* out = (float*)d_out;

    unsigned short* WB = (unsigned short*)d_ws;  // 16 KB repacked W
    const size_t wb_bytes = 16384;
    int* child = (int*)((char*)d_ws + wb_bytes); // num_out*8 ints
    const size_t child_bytes = (size_t)num_out * 8 * sizeof(int);

    prep_w_kernel<<<32, 256, 0, stream>>>(W, WB);

    if (ws_size >= wb_bytes + child_bytes) {
        // ---- atomic-free path ----
        hipMemsetAsync(child, 0xFF, child_bytes, stream);        // child = -1
        build_map_kernel<<<(n + 255) / 256, 256, 0, stream>>>(k_idx, out_idx, child, n);
        int blocks = (num_out + 63) / 64;                        // 64 voxels/block
        conv_gather_kernel<<<blocks, 256, 0, stream>>>(x, WB, child, out, num_out);
    } else {
        // ---- fallback: R1 atomic scatter ----
        hipMemsetAsync(d_out, 0, (size_t)out_size * sizeof(float), stream);
        int blocks = (n + 63) / 64;
        conv_atomic_kernel<<<blocks, 256, 0, stream>>>(x, WB, k_idx, out_idx, out, n);
    }
}